// Round 1
// 416.739 us; speedup vs baseline: 1.1475x; 1.1475x over previous
//
#include <hip/hip_runtime.h>

#define NN   512
#define TT   128
#define DD   128
#define NC   64     // rows per chunk
#define NCHUNK 8
#define SR   132    // hchd row stride (floats): rows 16B-aligned (528B), even bank spread
#define WR   68     // wTt row stride (floats): rows 16B-aligned (272B)

// Precompute per-head projected attention vectors (all fp32):
//   v_h[d] = sum_j W1[d][16h+j]*Wdst[j],  u_h[d] = sum_j W1[d][16h+j]*Wsrc[j]
//   ec[h]  = ba + sum_j b1[16h+j]*(Wsrc[j]+Wdst[j])
// ws layout: [0..1023] vtab[(h>>1)*256 + (d>>2)*8 + (h&1)*4 + (d&3)]
//            [2048..3071] utab[d*8+h] ; [3072..3079] ec[h]
__global__ void gat_prep(const float* __restrict__ W1, const float* __restrict__ b1,
                         const float* __restrict__ Wa, const float* __restrict__ ba,
                         float* __restrict__ ws)
{
  int idx = blockIdx.x*256 + threadIdx.x;   // 0..1023
  int d = idx >> 3, h = idx & 7;
  float v = 0.f, u = 0.f;
  for (int j = 0; j < 16; ++j){
    float w1 = W1[d*DD + h*16 + j];
    v += w1 * Wa[16 + j];
    u += w1 * Wa[j];
  }
  ws[(h>>1)*256 + (d>>2)*8 + (h&1)*4 + (d&3)] = v;
  ws[2048 + d*8 + h] = u;
  if (idx < 8){
    float ec = ba[0];
    for (int j = 0; j < 16; ++j)
      ec += b1[idx*16 + j] * (Wa[j] + Wa[16 + j]);
    ws[3072 + idx] = ec;
  }
}

// One block per (b,t). Flash-style online softmax over 8 chunks of 64 source rows.
// Wave w owns heads {2w, 2w+1} in the score phase (softmax state in registers).
// Agg phase: thread (dq=t&31, hh=t>>5) accumulates dims 4dq..4dq+3 of head hh.
// LDS trimmed to 40704 B (<= 40960) so 4 blocks/CU => all 1024 blocks co-resident.
__global__ __launch_bounds__(256, 4) void gat_main(
    const float* __restrict__ hin, const float* __restrict__ adj, const float* __restrict__ mask,
    const float* __restrict__ W1,  const float* __restrict__ b1,
    const float* __restrict__ W2,  const float* __restrict__ b2,
    const float* __restrict__ ws,  float* __restrict__ out)
{
  __shared__ __align__(16) float hchd[NC*SR];      // 33792 B (epilogue bufs aliased in)
  __shared__ __align__(16) float vsh[1024];        // vtab copy, 4 KB
  __shared__ __align__(16) float wTt[8*WR];        // per-head weight rows, 2176 B
  __shared__ float scaleS[8], ZL[8], SWL[8], Karr[8];
  __shared__ float targ[128];

  // epilogue-only buffers, aliased into hchd (dead after the chunk loop)
  float* const aggfin = hchd;                 // 8*SR = 1056 floats
  float* const catbuf = hchd + 8*SR;          // 256 floats @ [1056..1311]
  float* const oppart = hchd + 8*SR + 256;    // 256 floats @ [1312..1567]

  const int t    = threadIdx.x;
  const int bb   = blockIdx.x >> 7;
  const int tt   = blockIdx.x & 127;
  const int wave = t >> 6;
  const int lane = t & 63;

  #pragma unroll
  for (int r = 0; r < 4; ++r) vsh[t + 256*r] = ws[t + 256*r];

  float mrun0 = -1e30f, mrun1 = -1e30f;
  float Z0 = 0.f, Z1 = 0.f, SW0 = 0.f, SW1 = 0.f;
  float acc0 = 0.f, acc1 = 0.f, acc2 = 0.f, acc3 = 0.f;

  const int dq = t & 31;   // agg: dim-quad
  const int hh = t >> 5;   // agg: head

  const float4* __restrict__ hg4 = (const float4*)hin;
  // staging address hoist: vv = t + 256*i -> rl = (t>>5)+8i, dw = t&31
  // g = ((bb*NN + c*NC + rl)*TT + tt)*32 + dw ; dC = NC*TT*32 ; dI = 8*TT*32
  const long g0 = ((long)(bb*NN + (t>>5))*TT + tt)*(DD/4) + (t & 31);
  const int  l0 = (t>>5)*SR + 4*(t & 31);

  for (int c = 0; c < NCHUNK; ++c){
    // ---- stage chunk: 64 rows x 512B, float4 global -> b128 LDS ----
    {
      const long gc = g0 + (long)c * (NC*TT*(DD/4));
      #pragma unroll
      for (int i = 0; i < 8; ++i)
        *(float4*)&hchd[l0 + i*(8*SR)] = hg4[gc + (long)i*(8*TT*(DD/4))];
    }
    __syncthreads();

    if (c == 0){
      // row n=0 (contiguous at hchd[0..127]): target_h and score constant K_h
      if (t < 128){
        float a = b1[t];
        for (int d = 0; d < 128; ++d)
          a += hchd[d] * W1[d*DD + t];
        targ[t] = a;
      } else if (t < 136){
        int h8 = t - 128;
        float a = ws[3072 + h8];
        for (int d = 0; d < 128; ++d)
          a += hchd[d] * ws[2048 + d*8 + h8];
        Karr[h8] = a;
      }
      __syncthreads();
    }

    // ---- scores: s_h(row) = K_h + h_row . v_h ----
    float s0 = Karr[2*wave], s1 = Karr[2*wave + 1];
    {
      const float4* rowp = (const float4*)&hchd[lane*SR];
      const float4* vp   = (const float4*)&vsh[wave*256];
      #pragma unroll 8
      for (int j = 0; j < 32; ++j){
        float4 r4 = rowp[j];
        float4 va = vp[2*j], vb = vp[2*j + 1];
        s0 += r4.x*va.x + r4.y*va.y + r4.z*va.z + r4.w*va.w;
        s1 += r4.x*vb.x + r4.y*vb.y + r4.z*vb.z + r4.w*vb.w;
      }
    }
    const int ng = c*NC + lane;
    const float mv   = mask[(long)(bb*NN + ng)*TT + tt];
    const float av   = adj[(long)(bb*TT + tt)*NN + ng];
    const float inva = (av == 0.f) ? 1e-9f : (1.f/av);

    float sm0 = (mv > 0.f) ? s0 : -1e30f;
    float sm1 = (mv > 0.f) ? s1 : -1e30f;
    #pragma unroll
    for (int off = 32; off >= 1; off >>= 1){
      sm0 = fmaxf(sm0, __shfl_xor(sm0, off));
      sm1 = fmaxf(sm1, __shfl_xor(sm1, off));
    }
    float mn0 = fmaxf(mrun0, sm0), mn1 = fmaxf(mrun1, sm1);
    float sc0 = __expf(mrun0 - mn0), sc1 = __expf(mrun1 - mn1);
    mrun0 = mn0; mrun1 = mn1;

    float e0 = (mv > 0.f) ? __expf(s0 - mn0) : 0.f;
    float e1 = (mv > 0.f) ? __expf(s1 - mn1) : 0.f;
    float w0 = e0*inva, w1 = e1*inva;
    wTt[(2*wave)*WR + lane]     = w0;
    wTt[(2*wave + 1)*WR + lane] = w1;
    if (lane == 0){ scaleS[2*wave] = sc0; scaleS[2*wave + 1] = sc1; }

    float z0 = e0, z1 = e1, y0 = w0, y1 = w1;
    #pragma unroll
    for (int off = 32; off >= 1; off >>= 1){
      z0 += __shfl_xor(z0, off); z1 += __shfl_xor(z1, off);
      y0 += __shfl_xor(y0, off); y1 += __shfl_xor(y1, off);
    }
    Z0 = Z0*sc0 + z0;   Z1 = Z1*sc1 + z1;
    SW0 = SW0*sc0 + y0; SW1 = SW1*sc1 + y1;
    __syncthreads();     // wTt + scaleS visible

    // ---- agg: acc[hh][4dq..+3] += w[hh][n] * h[n][4dq..+3] ----
    {
      float scl = scaleS[hh];
      acc0 *= scl; acc1 *= scl; acc2 *= scl; acc3 *= scl;
      #pragma unroll 4
      for (int nb = 0; nb < 16; ++nb){
        float4 w4 = *(const float4*)&wTt[hh*WR + 4*nb];
        float4 r0 = *(const float4*)&hchd[(4*nb + 0)*SR + 4*dq];
        float4 r1 = *(const float4*)&hchd[(4*nb + 1)*SR + 4*dq];
        float4 r2 = *(const float4*)&hchd[(4*nb + 2)*SR + 4*dq];
        float4 r3 = *(const float4*)&hchd[(4*nb + 3)*SR + 4*dq];
        acc0 += w4.x*r0.x + w4.y*r1.x + w4.z*r2.x + w4.w*r3.x;
        acc1 += w4.x*r0.y + w4.y*r1.y + w4.z*r2.y + w4.w*r3.y;
        acc2 += w4.x*r0.z + w4.y*r1.z + w4.z*r2.z + w4.w*r3.z;
        acc3 += w4.x*r0.w + w4.y*r1.w + w4.z*r2.w + w4.w*r3.w;
      }
    }
    __syncthreads();     // chunk LDS dead; safe to restage
  }

  // ---- epilogue ----
  if (lane == 0){
    ZL[2*wave] = Z0;  ZL[2*wave + 1] = Z1;
    SWL[2*wave] = SW0; SWL[2*wave + 1] = SW1;
  }
  __syncthreads();
  {
    float invZ = 1.f / ZL[hh];
    float4 o; o.x = acc0*invZ; o.y = acc1*invZ; o.z = acc2*invZ; o.w = acc3*invZ;
    *(float4*)&aggfin[hh*SR + 4*dq] = o;
  }
  __syncthreads();

  // cat[0:128] = project weighted sum through W1 head-slice; cat[128:256] = target_h
  if (t < 128){
    int h2 = t >> 4;
    float a = (SWL[h2] / ZL[h2]) * b1[t];
    for (int d = 0; d < 128; ++d)
      a += aggfin[h2*SR + d] * W1[d*DD + t];
    catbuf[t]       = a;
    catbuf[128 + t] = targ[t];
  }
  __syncthreads();

  // out = cat @ W2 + b2 (2-way k-split)
  {
    int j = t & 127, kh = t >> 7;
    float o = 0.f;
    for (int k = kh*128; k < kh*128 + 128; ++k)
      o += catbuf[k] * W2[k*DD + j];
    oppart[t] = o;
  }
  __syncthreads();
  if (t < 128)
    out[(long)blockIdx.x*128 + t] = oppart[t] + oppart[128 + t] + b2[t];
}

extern "C" void kernel_launch(void* const* d_in, const int* in_sizes, int n_in,
                              void* d_out, int out_size, void* d_ws, size_t ws_size,
                              hipStream_t stream) {
  const float* h    = (const float*)d_in[0];
  const float* adj  = (const float*)d_in[1];
  const float* mask = (const float*)d_in[2];
  const float* W1   = (const float*)d_in[3];
  const float* b1   = (const float*)d_in[4];
  const float* Wa   = (const float*)d_in[5];
  const float* ba   = (const float*)d_in[6];
  const float* W2   = (const float*)d_in[7];
  const float* b2   = (const float*)d_in[8];
  float* ws  = (float*)d_ws;
  float* out = (float*)d_out;

  gat_prep<<<4, 256, 0, stream>>>(W1, b1, Wa, ba, ws);
  gat_main<<<1024, 256, 0, stream>>>(h, adj, mask, W1, b1, W2, b2, ws, out);
}